// Round 11
// baseline (143.979 us; speedup 1.0000x reference)
//
#include <hip/hip_runtime.h>
#include <hip/hip_bf16.h>
#include <cmath>

#define D_MODEL 768
#define NHEAD 12
#define HD 64
#define L_SEQ 2048
#define WIN 128
#define QKV_N (3 * D_MODEL)

typedef _Float16 half8 __attribute__((ext_vector_type(8)));
typedef _Float16 half4v __attribute__((ext_vector_type(4)));
typedef float floatx4 __attribute__((ext_vector_type(4)));

// ---------------------------------------------------------------------------
// Fused weight transposes: [0,432) W_qkv -> Wq16T; [432,576) W_o -> Wo16T.
// ---------------------------------------------------------------------------
#define CVT_B_BLKS (36 * 12)
#define CVT_C_BLKS (12 * 12)

__global__ __launch_bounds__(256) void cvt_fused_kernel(
    const float* __restrict__ W_qkv, _Float16* __restrict__ Wq16T,
    const float* __restrict__ W_o, _Float16* __restrict__ Wo16T) {
  __shared__ float tile[64][68];
  const int bid = blockIdx.x;
  const int tid = threadIdx.x;

  const float* In;
  _Float16* Out;
  int R, Cn, bx, by;
  if (bid < CVT_B_BLKS) {
    In = W_qkv; Out = Wq16T; R = D_MODEL; Cn = QKV_N;
    bx = bid % 36; by = bid / 36;
  } else {
    const int b = bid - CVT_B_BLKS;
    In = W_o; Out = Wo16T; R = D_MODEL; Cn = D_MODEL;
    bx = b % 12; by = b / 12;
  }
  const int r0 = by * 64, c0 = bx * 64;
  const int tr = tid >> 4, tc4 = (tid & 15) * 4;
#pragma unroll
  for (int rr = 0; rr < 4; ++rr) {
    const int r = rr * 16 + tr;
    const float4 v =
        *reinterpret_cast<const float4*>(&In[(size_t)(r0 + r) * Cn + c0 + tc4]);
    tile[r][tc4 + 0] = v.x;
    tile[r][tc4 + 1] = v.y;
    tile[r][tc4 + 2] = v.z;
    tile[r][tc4 + 3] = v.w;
  }
  __syncthreads();
#pragma unroll
  for (int cc = 0; cc < 4; ++cc) {
    const int c = cc * 16 + tr;
    half4v h = {(_Float16)tile[tc4 + 0][c], (_Float16)tile[tc4 + 1][c],
                (_Float16)tile[tc4 + 2][c], (_Float16)tile[tc4 + 3][c]};
    *reinterpret_cast<half4v*>(&Out[(size_t)(c0 + c) * R + r0 + tc4]) = h;
  }
}

// ---------------------------------------------------------------------------
// fp16 MFMA GEMM v3: double-buffered LDS, ONE barrier per K-step.
//   A32=true : A read as fp32 (emb), converted in-register during staging.
//   ROPE=true: fused RoPE+split epilogue -> q16/k16/v16 + v16T.
//   COMBINE=true: blocks with blockIdx.y==0 compute the CLS combine from
//   part[] into LDS and substitute it for A row 0 (J16 row 0 is garbage).
// C/D layout (m89-verified): col = lane&15, row = (lane>>4)*4 + j.
// ---------------------------------------------------------------------------
#define CSPLIT 32
#define CREC 66

template <int BM, int BN, typename OutT, bool ROPE, bool A32, bool COMBINE>
__global__ __launch_bounds__(256) void gemm16_kernel(
    const float* __restrict__ Af, const _Float16* __restrict__ Ah,
    const _Float16* __restrict__ BT, const float* __restrict__ bias,
    OutT* __restrict__ C, _Float16* __restrict__ q16,
    _Float16* __restrict__ k16, _Float16* __restrict__ v16,
    _Float16* __restrict__ v16T, const float* __restrict__ part, int M, int N,
    int K) {
  constexpr int LDK = 40;
  constexpr int MF = BM / 32;
  constexpr int NF = BN / 32;
  constexpr int CA = BM * 4 / 256;
  constexpr int CB = BN * 4 / 256;

  __shared__ __align__(16) _Float16 At[2 * BM * LDK];
  __shared__ __align__(16) _Float16 Bt[2 * BN * LDK];
  __shared__ __align__(16) _Float16 comb[COMBINE ? D_MODEL : 1];

  const int tid = threadIdx.x;
  const int row0 = blockIdx.y * BM;
  const int col0 = blockIdx.x * BN;
  const int wv = tid >> 6;
  const int lane = tid & 63;
  const int wr = wv >> 1;
  const int wc = wv & 1;
  const int lrow = lane & 15;
  const int lk = lane >> 4;
  const bool doComb = COMBINE && (blockIdx.y == 0);

  if constexpr (COMBINE) {
    if (doComb) {
#pragma unroll
      for (int j = 0; j < D_MODEL / 256; ++j) {
        const int c = tid + j * 256;
        const int h = c >> 6, d = c & 63;
        float gmax = -INFINITY;
#pragma unroll 8
        for (int sp = 0; sp < CSPLIT; ++sp)
          gmax = fmaxf(gmax, part[(size_t)(h * CSPLIT + sp) * CREC]);
        float total = 0.f, acc = 0.f;
#pragma unroll 8
        for (int sp = 0; sp < CSPLIT; ++sp) {
          const float* rec = &part[(size_t)(h * CSPLIT + sp) * CREC];
          const float mxi = rec[0];
          const float w = (mxi == -INFINITY) ? 0.f : __expf(mxi - gmax);
          total += w * rec[1];
          acc += w * rec[2 + d];
        }
        comb[c] = (_Float16)(acc / total);
      }
      __syncthreads();
    }
  }

  floatx4 acc[MF][NF];
#pragma unroll
  for (int m = 0; m < MF; ++m)
#pragma unroll
    for (int n = 0; n < NF; ++n) acc[m][n] = (floatx4){0.f, 0.f, 0.f, 0.f};

  half8 aR[CA], bR[CB];
  const int nt = K / 32;

  // ---- reg load for tile t ----
  auto load_regs = [&](int t) {
    const int k0 = t * 32;
#pragma unroll
    for (int i = 0; i < CA; ++i) {
      const int c = tid + i * 256, r = c >> 2, seg = c & 3;
      if constexpr (A32) {
        const float4 f0 = *reinterpret_cast<const float4*>(
            &Af[(size_t)(row0 + r) * K + k0 + seg * 8]);
        const float4 f1 = *reinterpret_cast<const float4*>(
            &Af[(size_t)(row0 + r) * K + k0 + seg * 8 + 4]);
        aR[i] = (half8){(_Float16)f0.x, (_Float16)f0.y, (_Float16)f0.z,
                        (_Float16)f0.w, (_Float16)f1.x, (_Float16)f1.y,
                        (_Float16)f1.z, (_Float16)f1.w};
      } else {
        if (COMBINE && doComb && r == 0) {
          aR[i] = *reinterpret_cast<const half8*>(&comb[k0 + seg * 8]);
        } else {
          aR[i] = *reinterpret_cast<const half8*>(
              &Ah[(size_t)(row0 + r) * K + k0 + seg * 8]);
        }
      }
    }
#pragma unroll
    for (int i = 0; i < CB; ++i) {
      const int c = tid + i * 256, r = c >> 2, seg = c & 3;
      bR[i] = *reinterpret_cast<const half8*>(
          &BT[(size_t)(col0 + r) * K + k0 + seg * 8]);
    }
  };
  auto store_lds = [&](int buf) {
    _Float16* a = &At[buf * BM * LDK];
    _Float16* b = &Bt[buf * BN * LDK];
#pragma unroll
    for (int i = 0; i < CA; ++i) {
      const int c = tid + i * 256, r = c >> 2, seg = c & 3;
      *reinterpret_cast<half8*>(&a[r * LDK + seg * 8]) = aR[i];
    }
#pragma unroll
    for (int i = 0; i < CB; ++i) {
      const int c = tid + i * 256, r = c >> 2, seg = c & 3;
      *reinterpret_cast<half8*>(&b[r * LDK + seg * 8]) = bR[i];
    }
  };

  load_regs(0);
  store_lds(0);
  int cur = 0;

  for (int t = 0; t < nt; ++t) {
    __syncthreads();  // buf[cur] ready; buf[cur^1] free
    if (t + 1 < nt) load_regs(t + 1);  // global latency hides under MFMA

    const _Float16* a = &At[cur * BM * LDK];
    const _Float16* b = &Bt[cur * BN * LDK];
    half8 af[MF], bf[NF];
#pragma unroll
    for (int m = 0; m < MF; ++m)
      af[m] = *reinterpret_cast<const half8*>(
          &a[(wr * (BM / 2) + m * 16 + lrow) * LDK + lk * 8]);
#pragma unroll
    for (int n = 0; n < NF; ++n)
      bf[n] = *reinterpret_cast<const half8*>(
          &b[(wc * (BN / 2) + n * 16 + lrow) * LDK + lk * 8]);
#pragma unroll
    for (int m = 0; m < MF; ++m)
#pragma unroll
      for (int n = 0; n < NF; ++n)
        acc[m][n] = __builtin_amdgcn_mfma_f32_16x16x32_f16(af[m], bf[n],
                                                           acc[m][n], 0, 0, 0);
    if (t + 1 < nt) store_lds(cur ^ 1);  // vmcnt drain lands after MFMA
    cur ^= 1;
  }

  if constexpr (!ROPE) {
#pragma unroll
    for (int m = 0; m < MF; ++m)
#pragma unroll
      for (int n = 0; n < NF; ++n) {
        const int col = col0 + wc * (BN / 2) + n * 16 + lrow;
        const float bb = bias[col];
#pragma unroll
        for (int j = 0; j < 4; ++j) {
          const int row = row0 + wr * (BM / 2) + m * 16 + lk * 4 + j;
          C[(size_t)row * N + col] = (OutT)(acc[m][n][j] + bb);
        }
      }
  } else {
    const int part_id = col0 / D_MODEL;          // 0=q 1=k 2=v
    const int h = ((col0 % D_MODEL) >> 6) + wc;  // head
    _Float16* dst = (part_id == 0) ? q16 : (part_id == 1) ? k16 : v16;
    float bb[4];
#pragma unroll
    for (int n = 0; n < 4; ++n) bb[n] = bias[col0 + wc * 64 + n * 16 + lrow];
    const float inv0 = exp2f(-0.4152410118609203f * (float)lrow);
    const float inv1 = inv0 * 0.01f;  // *10000^(-32/64)
#pragma unroll
    for (int m = 0; m < MF; ++m) {
#pragma unroll
      for (int j = 0; j < 4; ++j) {
        const int l = row0 + wr * (BM / 2) + m * 16 + lk * 4 + j;
        float val[4];
#pragma unroll
        for (int n = 0; n < 4; ++n) val[n] = acc[m][n][j] + bb[n];
        float o[4];
        if (part_id < 2) {
          float sn0, cs0, sn1, cs1;
          __sincosf((float)l * inv0, &sn0, &cs0);
          __sincosf((float)l * inv1, &sn1, &cs1);
          o[0] = val[0] * cs0 - val[2] * sn0;
          o[1] = val[1] * cs1 - val[3] * sn1;
          o[2] = val[0] * sn0 + val[2] * cs0;
          o[3] = val[1] * sn1 + val[3] * cs1;
        } else {
          o[0] = val[0]; o[1] = val[1]; o[2] = val[2]; o[3] = val[3];
        }
        const size_t base = ((size_t)h * L_SEQ + l) * HD + lrow;
#pragma unroll
        for (int n = 0; n < 4; ++n) dst[base + n * 16] = (_Float16)o[n];
      }
      if (part_id == 2) {
        const int lb = row0 + wr * (BM / 2) + m * 16 + lk * 4;
#pragma unroll
        for (int n = 0; n < 4; ++n) {
          const int col = h * HD + n * 16 + lrow;
          half4v hv = {(_Float16)(acc[m][n][0] + bb[n]),
                       (_Float16)(acc[m][n][1] + bb[n]),
                       (_Float16)(acc[m][n][2] + bb[n]),
                       (_Float16)(acc[m][n][3] + bb[n])};
          *reinterpret_cast<half4v*>(&v16T[(size_t)col * L_SEQ + lb]) = hv;
        }
      }
    }
  }
}

// ---------------------------------------------------------------------------
// Attention megakernel (unchanged from R10, validated).
// ---------------------------------------------------------------------------
#define TL 32
#define SLOTS 160
#define LDH 72
#define LDS_S 168
#define LDVT 168
#define CROWS (L_SEQ / CSPLIT)  // 64

__global__ __launch_bounds__(256) void attn_mega_kernel(
    const _Float16* __restrict__ q16, const _Float16* __restrict__ k16,
    const _Float16* __restrict__ v16, const _Float16* __restrict__ v16T,
    const int* __restrict__ mask, _Float16* __restrict__ joined,
    float* __restrict__ part) {
  const int h = blockIdx.y;
  const int tid = threadIdx.x;
  const float scale = 0.036084391824351615f;  // 1/sqrt(768)

  __shared__ __align__(16) _Float16 kv16[SLOTS * LDH];
  __shared__ __align__(16) float sS[TL * LDS_S];
  __shared__ __align__(16) _Float16 q16l[TL * LDH];
  __shared__ float vbias[SLOTS];

  if (blockIdx.x < (L_SEQ / TL)) {
    const int l0 = blockIdx.x * TL;
    const _Float16* kh = k16 + (size_t)h * L_SEQ * HD;
    const _Float16* qh = q16 + (size_t)h * L_SEQ * HD;

    {
      const int row = tid >> 3, oct = (tid & 7) * 8;
      *reinterpret_cast<half8*>(&q16l[row * LDH + oct]) =
          *reinterpret_cast<const half8*>(&qh[(size_t)(l0 + row) * HD + oct]);
    }
    const _Float16* kwin = kh + (size_t)(l0 - WIN / 2) * HD;
#pragma unroll
    for (int c = tid; c < SLOTS * 8; c += 256) {
      const int slot = c >> 3, oct = (c & 7) * 8;
      *reinterpret_cast<half8*>(&kv16[slot * LDH + oct]) =
          *reinterpret_cast<const half8*>(&kwin[(size_t)slot * HD + oct]);
    }
    if (tid < SLOTS) {
      const int raw = l0 + tid - WIN / 2;
      const int idx = min(max(raw, 0), L_SEQ - 1);
      vbias[tid] =
          ((raw >= 0) && (raw < L_SEQ) && (mask[idx] != 0)) ? 0.f : -INFINITY;
    }
    __syncthreads();

    const int wv = tid >> 6, lane = tid & 63;
    const int wr = wv >> 1, wc = wv & 1;
    const int lcol = lane & 15, loct = (lane >> 4) * 8;

    floatx4 accS[5];
#pragma unroll
    for (int f = 0; f < 5; ++f) accS[f] = (floatx4){0.f, 0.f, 0.f, 0.f};
#pragma unroll
    for (int ks = 0; ks < 2; ++ks) {
      const half8 af = *reinterpret_cast<const half8*>(
          &q16l[(wr * 16 + lcol) * LDH + ks * 32 + loct]);
#pragma unroll
      for (int f = 0; f < 5; ++f) {
        const half8 bf = *reinterpret_cast<const half8*>(
            &kv16[(wc * 80 + f * 16 + lcol) * LDH + ks * 32 + loct]);
        accS[f] =
            __builtin_amdgcn_mfma_f32_16x16x32_f16(af, bf, accS[f], 0, 0, 0);
      }
    }
#pragma unroll
    for (int f = 0; f < 5; ++f) {
      const int slot = wc * 80 + f * 16 + lcol;
      const float vb = vbias[slot];
#pragma unroll
      for (int j = 0; j < 4; ++j) {
        const int row = wr * 16 + (lane >> 4) * 4 + j;
        const bool inband = (slot >= row) && (slot <= row + WIN - 1);
        sS[row * LDS_S + slot] = inband ? (accS[f][j] * scale + vb) : -INFINITY;
      }
    }
    __syncthreads();

    _Float16* vt = kv16;
    const _Float16* vtg = v16T + (size_t)h * HD * L_SEQ + (l0 - WIN / 2);
#pragma unroll
    for (int c = tid; c < HD * 20; c += 256) {
      const int d = c / 20, seg = c % 20;
      *reinterpret_cast<half8*>(&vt[d * LDVT + seg * 8]) =
          *reinterpret_cast<const half8*>(&vtg[(size_t)d * L_SEQ + seg * 8]);
    }

    const int r = tid >> 3, wg = tid & 7;
    float pv[20];
    float mloc = -INFINITY;
#pragma unroll
    for (int i = 0; i < 20; ++i) {
      pv[i] = sS[r * LDS_S + wg * 20 + i];
      mloc = fmaxf(mloc, pv[i]);
    }
#pragma unroll
    for (int m = 1; m < 8; m <<= 1) mloc = fmaxf(mloc, __shfl_xor(mloc, m));
    float ssum = 0.f;
#pragma unroll
    for (int i = 0; i < 20; ++i) {
      pv[i] = __expf(pv[i] - mloc);
      ssum += pv[i];
    }
#pragma unroll
    for (int m = 1; m < 8; m <<= 1) ssum += __shfl_xor(ssum, m);
    const float rcp = 1.0f / ssum;
    __syncthreads();

    _Float16* pS = reinterpret_cast<_Float16*>(sS);
#pragma unroll
    for (int i = 0; i < 20; ++i)
      pS[r * (2 * LDS_S) + wg * 20 + i] = (_Float16)(pv[i] * rcp);
    __syncthreads();

    floatx4 accO[2];
    accO[0] = (floatx4){0.f, 0.f, 0.f, 0.f};
    accO[1] = (floatx4){0.f, 0.f, 0.f, 0.f};
#pragma unroll
    for (int ks = 0; ks < 5; ++ks) {
      const half8 ap = *reinterpret_cast<const half8*>(
          &pS[(wr * 16 + lcol) * (2 * LDS_S) + ks * 32 + loct]);
#pragma unroll
      for (int cf = 0; cf < 2; ++cf) {
        const half8 bv = *reinterpret_cast<const half8*>(
            &vt[(wc * 32 + cf * 16 + lcol) * LDVT + ks * 32 + loct]);
        accO[cf] =
            __builtin_amdgcn_mfma_f32_16x16x32_f16(ap, bv, accO[cf], 0, 0, 0);
      }
    }
#pragma unroll
    for (int cf = 0; cf < 2; ++cf)
#pragma unroll
      for (int j = 0; j < 4; ++j) {
        const int row = wr * 16 + (lane >> 4) * 4 + j;
        const int d = wc * 32 + cf * 16 + lcol;
        joined[(size_t)(l0 + row) * D_MODEL + h * HD + d] =
            (_Float16)accO[cf][j];
      }
  } else {
    const int sp = blockIdx.x - (L_SEQ / TL);
    const int l0 = sp * CROWS;
    float* scS = sS;
    float* red = sS + CROWS;
    float* pvS = sS + CROWS + 256;

    const _Float16* kh = k16 + (size_t)h * L_SEQ * HD;
    const _Float16* vh = v16 + (size_t)h * L_SEQ * HD;

    const int lq = tid >> 4;
    const int dq = tid & 15;
    const half4v q4 =
        *reinterpret_cast<const half4v*>(&q16[(size_t)h * L_SEQ * HD + dq * 4]);
#pragma unroll
    for (int it = 0; it < CROWS / 16; ++it) {
      const int l = l0 + it * 16 + lq;
      const half4v k4 =
          *reinterpret_cast<const half4v*>(&kh[(size_t)l * HD + dq * 4]);
      float p = (float)q4[0] * (float)k4[0] + (float)q4[1] * (float)k4[1] +
                (float)q4[2] * (float)k4[2] + (float)q4[3] * (float)k4[3];
#pragma unroll
      for (int m = 1; m < 16; m <<= 1) p += __shfl_xor(p, m);
      if (dq == 0) scS[it * 16 + lq] = (mask[l] != 0) ? p * scale : -INFINITY;
    }
    __syncthreads();

    red[tid] = (tid < CROWS) ? scS[tid] : -INFINITY;
    __syncthreads();
    for (int off = 128; off > 0; off >>= 1) {
      if (tid < off) red[tid] = fmaxf(red[tid], red[tid + off]);
      __syncthreads();
    }
    const float mx = red[0];
    __syncthreads();

    float e = 0.f;
    if (tid < CROWS) {
      e = (mx == -INFINITY) ? 0.f : __expf(scS[tid] - mx);
      scS[tid] = e;
    }
    red[tid] = e;
    __syncthreads();
    for (int off = 128; off > 0; off >>= 1) {
      if (tid < off) red[tid] += red[tid + off];
      __syncthreads();
    }
    const float lsum = red[0];
    __syncthreads();

    const int lg = tid >> 6;
    const int d = tid & 63;
    float acc = 0.f;
#pragma unroll 8
    for (int it = 0; it < CROWS / 4; ++it) {
      const int ll = lg + it * 4;
      acc += scS[ll] * (float)vh[(size_t)(l0 + ll) * HD + d];
    }
    pvS[lg * HD + d] = acc;
    __syncthreads();

    float* rec = &part[(size_t)(h * CSPLIT + sp) * CREC];
    if (tid == 0) {
      rec[0] = mx;
      rec[1] = lsum;
    }
    if (tid < HD)
      rec[2 + tid] = pvS[0 * HD + tid] + pvS[1 * HD + tid] +
                     pvS[2 * HD + tid] + pvS[3 * HD + tid];
  }
}

// ---------------------------------------------------------------------------
extern "C" void kernel_launch(void* const* d_in, const int* in_sizes, int n_in,
                              void* d_out, int out_size, void* d_ws,
                              size_t ws_size, hipStream_t stream) {
  const float* emb   = (const float*)d_in[0];
  const int*   mask  = (const int*)d_in[1];
  const float* W_qkv = (const float*)d_in[2];
  const float* b_qkv = (const float*)d_in[3];
  const float* W_o   = (const float*)d_in[4];
  const float* b_o   = (const float*)d_in[5];
  float* out = (float*)d_out;

  _Float16* hp = (_Float16*)d_ws;
  _Float16* Wq16T = hp;                                      // 2304*768
  _Float16* Wo16T = Wq16T + (size_t)QKV_N * D_MODEL;         // 768*768
  _Float16* q16   = Wo16T + (size_t)D_MODEL * D_MODEL;       // 12*2048*64
  _Float16* k16   = q16 + (size_t)NHEAD * L_SEQ * HD;
  _Float16* v16   = k16 + (size_t)NHEAD * L_SEQ * HD;
  _Float16* v16T  = v16 + (size_t)NHEAD * L_SEQ * HD;        // [768][2048]
  _Float16* J16   = v16T + (size_t)D_MODEL * L_SEQ;          // 2048*768
  float*    part  = (float*)(J16 + (size_t)L_SEQ * D_MODEL); // 12*32*66

  cvt_fused_kernel<<<CVT_B_BLKS + CVT_C_BLKS, 256, 0, stream>>>(
      W_qkv, Wq16T, W_o, Wo16T);

  // QKV GEMM (A = emb fp32 direct) + fused RoPE/split epilogue
  gemm16_kernel<64, 128, _Float16, true, true, false>
      <<<dim3(QKV_N / 128, L_SEQ / 64), 256, 0, stream>>>(
          emb, (const _Float16*)nullptr, Wq16T, b_qkv, (_Float16*)nullptr, q16,
          k16, v16, v16T, (const float*)nullptr, L_SEQ, QKV_N, D_MODEL);

  attn_mega_kernel<<<dim3(L_SEQ / TL + CSPLIT, NHEAD), 256, 0, stream>>>(
      q16, k16, v16, v16T, mask, J16, part);

  // Output GEMM + fused CLS combine (row 0 of J16 replaced from part[])
  gemm16_kernel<64, 64, float, false, false, true>
      <<<dim3(D_MODEL / 64, L_SEQ / 64), 256, 0, stream>>>(
          (const float*)nullptr, J16, Wo16T, b_o, out, (_Float16*)nullptr,
          (_Float16*)nullptr, (_Float16*)nullptr, (_Float16*)nullptr, part,
          L_SEQ, D_MODEL, D_MODEL);
}

// Round 12
// 125.439 us; speedup vs baseline: 1.1478x; 1.1478x over previous
//
#include <hip/hip_runtime.h>
#include <hip/hip_bf16.h>
#include <cmath>

#define D_MODEL 768
#define NHEAD 12
#define HD 64
#define L_SEQ 2048
#define WIN 128
#define QKV_N (3 * D_MODEL)

typedef _Float16 half8 __attribute__((ext_vector_type(8)));
typedef _Float16 half4v __attribute__((ext_vector_type(4)));
typedef float floatx4 __attribute__((ext_vector_type(4)));

// ---------------------------------------------------------------------------
// Fused conversions: [0,1536) cvt emb->fp16; [1536,1968) transpose W_qkv;
// [1968,2112) transpose W_o.  (R10-identical)
// ---------------------------------------------------------------------------
#define CVT_A_BLKS 1536
#define CVT_B_BLKS (36 * 12)
#define CVT_C_BLKS (12 * 12)

__global__ __launch_bounds__(256) void cvt_fused_kernel(
    const float* __restrict__ emb, _Float16* __restrict__ A16,
    const float* __restrict__ W_qkv, _Float16* __restrict__ Wq16T,
    const float* __restrict__ W_o, _Float16* __restrict__ Wo16T) {
  __shared__ float tile[64][68];
  const int bid = blockIdx.x;
  const int tid = threadIdx.x;

  if (bid < CVT_A_BLKS) {
    const int i = (bid * 256 + tid) * 4;
    const float4 v = *reinterpret_cast<const float4*>(&emb[i]);
    half4v h = {(_Float16)v.x, (_Float16)v.y, (_Float16)v.z, (_Float16)v.w};
    *reinterpret_cast<half4v*>(&A16[i]) = h;
    return;
  }
  const float* In;
  _Float16* Out;
  int R, Cn, bx, by;
  if (bid < CVT_A_BLKS + CVT_B_BLKS) {
    const int b = bid - CVT_A_BLKS;
    In = W_qkv; Out = Wq16T; R = D_MODEL; Cn = QKV_N;
    bx = b % 36; by = b / 36;
  } else {
    const int b = bid - CVT_A_BLKS - CVT_B_BLKS;
    In = W_o; Out = Wo16T; R = D_MODEL; Cn = D_MODEL;
    bx = b % 12; by = b / 12;
  }
  const int r0 = by * 64, c0 = bx * 64;
  const int tr = tid >> 4, tc4 = (tid & 15) * 4;
#pragma unroll
  for (int rr = 0; rr < 4; ++rr) {
    const int r = rr * 16 + tr;
    const float4 v =
        *reinterpret_cast<const float4*>(&In[(size_t)(r0 + r) * Cn + c0 + tc4]);
    tile[r][tc4 + 0] = v.x;
    tile[r][tc4 + 1] = v.y;
    tile[r][tc4 + 2] = v.z;
    tile[r][tc4 + 3] = v.w;
  }
  __syncthreads();
#pragma unroll
  for (int cc = 0; cc < 4; ++cc) {
    const int c = cc * 16 + tr;
    half4v h = {(_Float16)tile[tc4 + 0][c], (_Float16)tile[tc4 + 1][c],
                (_Float16)tile[tc4 + 2][c], (_Float16)tile[tc4 + 3][c]};
    *reinterpret_cast<half4v*>(&Out[(size_t)(c0 + c) * R + r0 + tc4]) = h;
  }
}

// ---------------------------------------------------------------------------
// fp16 MFMA GEMM — R10 base + ISOLATED change: double-buffered LDS, ONE
// barrier per K-step (stores for t+1 issued after MFMA on t).
// C/D layout (m89-verified): col = lane&15, row = (lane>>4)*4 + j.
// ---------------------------------------------------------------------------
template <int BM, int BN, typename OutT, bool ROPE>
__global__ __launch_bounds__(256) void gemm16_kernel(
    const _Float16* __restrict__ A, const _Float16* __restrict__ BT,
    const float* __restrict__ bias, OutT* __restrict__ C,
    _Float16* __restrict__ q16, _Float16* __restrict__ k16,
    _Float16* __restrict__ v16, _Float16* __restrict__ v16T, int M, int N,
    int K) {
  constexpr int LDK = 40;
  constexpr int MF = BM / 32;
  constexpr int NF = BN / 32;
  constexpr int CA = BM * 4 / 256;
  constexpr int CB = BN * 4 / 256;

  __shared__ __align__(16) _Float16 At[2 * BM * LDK];
  __shared__ __align__(16) _Float16 Bt[2 * BN * LDK];

  const int tid = threadIdx.x;
  const int row0 = blockIdx.y * BM;
  const int col0 = blockIdx.x * BN;
  const int wv = tid >> 6;
  const int lane = tid & 63;
  const int wr = wv >> 1;
  const int wc = wv & 1;
  const int lrow = lane & 15;
  const int lk = lane >> 4;

  floatx4 acc[MF][NF];
#pragma unroll
  for (int m = 0; m < MF; ++m)
#pragma unroll
    for (int n = 0; n < NF; ++n) acc[m][n] = (floatx4){0.f, 0.f, 0.f, 0.f};

  half8 aR[CA], bR[CB];
  const int nt = K / 32;

#pragma unroll
  for (int i = 0; i < CA; ++i) {
    const int c = tid + i * 256, r = c >> 2, seg = c & 3;
    aR[i] = *reinterpret_cast<const half8*>(&A[(size_t)(row0 + r) * K + seg * 8]);
  }
#pragma unroll
  for (int i = 0; i < CB; ++i) {
    const int c = tid + i * 256, r = c >> 2, seg = c & 3;
    bR[i] =
        *reinterpret_cast<const half8*>(&BT[(size_t)(col0 + r) * K + seg * 8]);
  }
  // store tile 0 into buf 0
  {
#pragma unroll
    for (int i = 0; i < CA; ++i) {
      const int c = tid + i * 256, r = c >> 2, seg = c & 3;
      *reinterpret_cast<half8*>(&At[r * LDK + seg * 8]) = aR[i];
    }
#pragma unroll
    for (int i = 0; i < CB; ++i) {
      const int c = tid + i * 256, r = c >> 2, seg = c & 3;
      *reinterpret_cast<half8*>(&Bt[r * LDK + seg * 8]) = bR[i];
    }
  }
  int cur = 0;

  for (int t = 0; t < nt; ++t) {
    __syncthreads();  // buf[cur] ready; all reads of buf[cur^1] (iter t-1) done
    if (t + 1 < nt) {  // issue next-tile global loads; hide under MFMA
      const int k0 = (t + 1) * 32;
#pragma unroll
      for (int i = 0; i < CA; ++i) {
        const int c = tid + i * 256, r = c >> 2, seg = c & 3;
        aR[i] = *reinterpret_cast<const half8*>(
            &A[(size_t)(row0 + r) * K + k0 + seg * 8]);
      }
#pragma unroll
      for (int i = 0; i < CB; ++i) {
        const int c = tid + i * 256, r = c >> 2, seg = c & 3;
        bR[i] = *reinterpret_cast<const half8*>(
            &BT[(size_t)(col0 + r) * K + k0 + seg * 8]);
      }
    }

    const _Float16* a = &At[cur * BM * LDK];
    const _Float16* b = &Bt[cur * BN * LDK];
    half8 af[MF], bf[NF];
#pragma unroll
    for (int m = 0; m < MF; ++m)
      af[m] = *reinterpret_cast<const half8*>(
          &a[(wr * (BM / 2) + m * 16 + lrow) * LDK + lk * 8]);
#pragma unroll
    for (int n = 0; n < NF; ++n)
      bf[n] = *reinterpret_cast<const half8*>(
          &b[(wc * (BN / 2) + n * 16 + lrow) * LDK + lk * 8]);
#pragma unroll
    for (int m = 0; m < MF; ++m)
#pragma unroll
      for (int n = 0; n < NF; ++n)
        acc[m][n] = __builtin_amdgcn_mfma_f32_16x16x32_f16(af[m], bf[n],
                                                           acc[m][n], 0, 0, 0);

    if (t + 1 < nt) {  // vmcnt drain lands here, after MFMA
      _Float16* a2 = &At[(cur ^ 1) * BM * LDK];
      _Float16* b2 = &Bt[(cur ^ 1) * BN * LDK];
#pragma unroll
      for (int i = 0; i < CA; ++i) {
        const int c = tid + i * 256, r = c >> 2, seg = c & 3;
        *reinterpret_cast<half8*>(&a2[r * LDK + seg * 8]) = aR[i];
      }
#pragma unroll
      for (int i = 0; i < CB; ++i) {
        const int c = tid + i * 256, r = c >> 2, seg = c & 3;
        *reinterpret_cast<half8*>(&b2[r * LDK + seg * 8]) = bR[i];
      }
    }
    cur ^= 1;
  }

  if constexpr (!ROPE) {
#pragma unroll
    for (int m = 0; m < MF; ++m)
#pragma unroll
      for (int n = 0; n < NF; ++n) {
        const int col = col0 + wc * (BN / 2) + n * 16 + lrow;
        const float bb = bias[col];
#pragma unroll
        for (int j = 0; j < 4; ++j) {
          const int row = row0 + wr * (BM / 2) + m * 16 + lk * 4 + j;
          C[(size_t)row * N + col] = (OutT)(acc[m][n][j] + bb);
        }
      }
  } else {
    const int part = col0 / D_MODEL;             // 0=q 1=k 2=v
    const int h = ((col0 % D_MODEL) >> 6) + wc;  // head
    _Float16* dst = (part == 0) ? q16 : (part == 1) ? k16 : v16;
    float bb[4];
#pragma unroll
    for (int n = 0; n < 4; ++n) bb[n] = bias[col0 + wc * 64 + n * 16 + lrow];
    const float inv0 = exp2f(-0.4152410118609203f * (float)lrow);
    const float inv1 = inv0 * 0.01f;  // *10000^(-32/64)
#pragma unroll
    for (int m = 0; m < MF; ++m) {
#pragma unroll
      for (int j = 0; j < 4; ++j) {
        const int l = row0 + wr * (BM / 2) + m * 16 + lk * 4 + j;
        float val[4];
#pragma unroll
        for (int n = 0; n < 4; ++n) val[n] = acc[m][n][j] + bb[n];
        float o[4];
        if (part < 2) {
          float sn0, cs0, sn1, cs1;
          __sincosf((float)l * inv0, &sn0, &cs0);
          __sincosf((float)l * inv1, &sn1, &cs1);
          o[0] = val[0] * cs0 - val[2] * sn0;
          o[1] = val[1] * cs1 - val[3] * sn1;
          o[2] = val[0] * sn0 + val[2] * cs0;
          o[3] = val[1] * sn1 + val[3] * cs1;
        } else {
          o[0] = val[0]; o[1] = val[1]; o[2] = val[2]; o[3] = val[3];
        }
        const size_t base = ((size_t)h * L_SEQ + l) * HD + lrow;
#pragma unroll
        for (int n = 0; n < 4; ++n) dst[base + n * 16] = (_Float16)o[n];
      }
      if (part == 2) {
        const int lb = row0 + wr * (BM / 2) + m * 16 + lk * 4;
#pragma unroll
        for (int n = 0; n < 4; ++n) {
          const int col = h * HD + n * 16 + lrow;
          half4v hv = {(_Float16)(acc[m][n][0] + bb[n]),
                       (_Float16)(acc[m][n][1] + bb[n]),
                       (_Float16)(acc[m][n][2] + bb[n]),
                       (_Float16)(acc[m][n][3] + bb[n])};
          *reinterpret_cast<half4v*>(&v16T[(size_t)col * L_SEQ + lb]) = hv;
        }
      }
    }
  }
}

// ---------------------------------------------------------------------------
// Attention megakernel (R10-identical, validated).
// ---------------------------------------------------------------------------
#define TL 32
#define SLOTS 160
#define LDH 72
#define LDS_S 168
#define LDVT 168
#define CSPLIT 32
#define CROWS (L_SEQ / CSPLIT)  // 64
#define CREC 66

__global__ __launch_bounds__(256) void attn_mega_kernel(
    const _Float16* __restrict__ q16, const _Float16* __restrict__ k16,
    const _Float16* __restrict__ v16, const _Float16* __restrict__ v16T,
    const int* __restrict__ mask, _Float16* __restrict__ joined,
    float* __restrict__ part) {
  const int h = blockIdx.y;
  const int tid = threadIdx.x;
  const float scale = 0.036084391824351615f;  // 1/sqrt(768)

  __shared__ __align__(16) _Float16 kv16[SLOTS * LDH];
  __shared__ __align__(16) float sS[TL * LDS_S];
  __shared__ __align__(16) _Float16 q16l[TL * LDH];
  __shared__ float vbias[SLOTS];

  if (blockIdx.x < (L_SEQ / TL)) {
    const int l0 = blockIdx.x * TL;
    const _Float16* kh = k16 + (size_t)h * L_SEQ * HD;
    const _Float16* qh = q16 + (size_t)h * L_SEQ * HD;

    {
      const int row = tid >> 3, oct = (tid & 7) * 8;
      *reinterpret_cast<half8*>(&q16l[row * LDH + oct]) =
          *reinterpret_cast<const half8*>(&qh[(size_t)(l0 + row) * HD + oct]);
    }
    const _Float16* kwin = kh + (size_t)(l0 - WIN / 2) * HD;
#pragma unroll
    for (int c = tid; c < SLOTS * 8; c += 256) {
      const int slot = c >> 3, oct = (c & 7) * 8;
      *reinterpret_cast<half8*>(&kv16[slot * LDH + oct]) =
          *reinterpret_cast<const half8*>(&kwin[(size_t)slot * HD + oct]);
    }
    if (tid < SLOTS) {
      const int raw = l0 + tid - WIN / 2;
      const int idx = min(max(raw, 0), L_SEQ - 1);
      vbias[tid] =
          ((raw >= 0) && (raw < L_SEQ) && (mask[idx] != 0)) ? 0.f : -INFINITY;
    }
    __syncthreads();

    const int wv = tid >> 6, lane = tid & 63;
    const int wr = wv >> 1, wc = wv & 1;
    const int lcol = lane & 15, loct = (lane >> 4) * 8;

    floatx4 accS[5];
#pragma unroll
    for (int f = 0; f < 5; ++f) accS[f] = (floatx4){0.f, 0.f, 0.f, 0.f};
#pragma unroll
    for (int ks = 0; ks < 2; ++ks) {
      const half8 af = *reinterpret_cast<const half8*>(
          &q16l[(wr * 16 + lcol) * LDH + ks * 32 + loct]);
#pragma unroll
      for (int f = 0; f < 5; ++f) {
        const half8 bf = *reinterpret_cast<const half8*>(
            &kv16[(wc * 80 + f * 16 + lcol) * LDH + ks * 32 + loct]);
        accS[f] =
            __builtin_amdgcn_mfma_f32_16x16x32_f16(af, bf, accS[f], 0, 0, 0);
      }
    }
#pragma unroll
    for (int f = 0; f < 5; ++f) {
      const int slot = wc * 80 + f * 16 + lcol;
      const float vb = vbias[slot];
#pragma unroll
      for (int j = 0; j < 4; ++j) {
        const int row = wr * 16 + (lane >> 4) * 4 + j;
        const bool inband = (slot >= row) && (slot <= row + WIN - 1);
        sS[row * LDS_S + slot] = inband ? (accS[f][j] * scale + vb) : -INFINITY;
      }
    }
    __syncthreads();

    _Float16* vt = kv16;
    const _Float16* vtg = v16T + (size_t)h * HD * L_SEQ + (l0 - WIN / 2);
#pragma unroll
    for (int c = tid; c < HD * 20; c += 256) {
      const int d = c / 20, seg = c % 20;
      *reinterpret_cast<half8*>(&vt[d * LDVT + seg * 8]) =
          *reinterpret_cast<const half8*>(&vtg[(size_t)d * L_SEQ + seg * 8]);
    }

    const int r = tid >> 3, wg = tid & 7;
    float pv[20];
    float mloc = -INFINITY;
#pragma unroll
    for (int i = 0; i < 20; ++i) {
      pv[i] = sS[r * LDS_S + wg * 20 + i];
      mloc = fmaxf(mloc, pv[i]);
    }
#pragma unroll
    for (int m = 1; m < 8; m <<= 1) mloc = fmaxf(mloc, __shfl_xor(mloc, m));
    float ssum = 0.f;
#pragma unroll
    for (int i = 0; i < 20; ++i) {
      pv[i] = __expf(pv[i] - mloc);
      ssum += pv[i];
    }
#pragma unroll
    for (int m = 1; m < 8; m <<= 1) ssum += __shfl_xor(ssum, m);
    const float rcp = 1.0f / ssum;
    __syncthreads();

    _Float16* pS = reinterpret_cast<_Float16*>(sS);
#pragma unroll
    for (int i = 0; i < 20; ++i)
      pS[r * (2 * LDS_S) + wg * 20 + i] = (_Float16)(pv[i] * rcp);
    __syncthreads();

    floatx4 accO[2];
    accO[0] = (floatx4){0.f, 0.f, 0.f, 0.f};
    accO[1] = (floatx4){0.f, 0.f, 0.f, 0.f};
#pragma unroll
    for (int ks = 0; ks < 5; ++ks) {
      const half8 ap = *reinterpret_cast<const half8*>(
          &pS[(wr * 16 + lcol) * (2 * LDS_S) + ks * 32 + loct]);
#pragma unroll
      for (int cf = 0; cf < 2; ++cf) {
        const half8 bv = *reinterpret_cast<const half8*>(
            &vt[(wc * 32 + cf * 16 + lcol) * LDVT + ks * 32 + loct]);
        accO[cf] =
            __builtin_amdgcn_mfma_f32_16x16x32_f16(ap, bv, accO[cf], 0, 0, 0);
      }
    }
#pragma unroll
    for (int cf = 0; cf < 2; ++cf)
#pragma unroll
      for (int j = 0; j < 4; ++j) {
        const int row = wr * 16 + (lane >> 4) * 4 + j;
        const int d = wc * 32 + cf * 16 + lcol;
        joined[(size_t)(l0 + row) * D_MODEL + h * HD + d] =
            (_Float16)accO[cf][j];
      }
  } else {
    const int sp = blockIdx.x - (L_SEQ / TL);
    const int l0 = sp * CROWS;
    float* scS = sS;
    float* red = sS + CROWS;
    float* pvS = sS + CROWS + 256;

    const _Float16* kh = k16 + (size_t)h * L_SEQ * HD;
    const _Float16* vh = v16 + (size_t)h * L_SEQ * HD;

    const int lq = tid >> 4;
    const int dq = tid & 15;
    const half4v q4 =
        *reinterpret_cast<const half4v*>(&q16[(size_t)h * L_SEQ * HD + dq * 4]);
#pragma unroll
    for (int it = 0; it < CROWS / 16; ++it) {
      const int l = l0 + it * 16 + lq;
      const half4v k4 =
          *reinterpret_cast<const half4v*>(&kh[(size_t)l * HD + dq * 4]);
      float p = (float)q4[0] * (float)k4[0] + (float)q4[1] * (float)k4[1] +
                (float)q4[2] * (float)k4[2] + (float)q4[3] * (float)k4[3];
#pragma unroll
      for (int m = 1; m < 16; m <<= 1) p += __shfl_xor(p, m);
      if (dq == 0) scS[it * 16 + lq] = (mask[l] != 0) ? p * scale : -INFINITY;
    }
    __syncthreads();

    red[tid] = (tid < CROWS) ? scS[tid] : -INFINITY;
    __syncthreads();
    for (int off = 128; off > 0; off >>= 1) {
      if (tid < off) red[tid] = fmaxf(red[tid], red[tid + off]);
      __syncthreads();
    }
    const float mx = red[0];
    __syncthreads();

    float e = 0.f;
    if (tid < CROWS) {
      e = (mx == -INFINITY) ? 0.f : __expf(scS[tid] - mx);
      scS[tid] = e;
    }
    red[tid] = e;
    __syncthreads();
    for (int off = 128; off > 0; off >>= 1) {
      if (tid < off) red[tid] += red[tid + off];
      __syncthreads();
    }
    const float lsum = red[0];
    __syncthreads();

    const int lg = tid >> 6;
    const int d = tid & 63;
    float acc = 0.f;
#pragma unroll 8
    for (int it = 0; it < CROWS / 4; ++it) {
      const int ll = lg + it * 4;
      acc += scS[ll] * (float)vh[(size_t)(l0 + ll) * HD + d];
    }
    pvS[lg * HD + d] = acc;
    __syncthreads();

    float* rec = &part[(size_t)(h * CSPLIT + sp) * CREC];
    if (tid == 0) {
      rec[0] = mx;
      rec[1] = lsum;
    }
    if (tid < HD)
      rec[2 + tid] = pvS[0 * HD + tid] + pvS[1 * HD + tid] +
                     pvS[2 * HD + tid] + pvS[3 * HD + tid];
  }
}

__global__ __launch_bounds__(64) void cls_combine_kernel(
    const float* __restrict__ part, _Float16* __restrict__ joined) {
  const int h = blockIdx.x;
  const int d = threadIdx.x;

  float gmax = -INFINITY;
#pragma unroll
  for (int sp = 0; sp < CSPLIT; ++sp)
    gmax = fmaxf(gmax, part[(size_t)(h * CSPLIT + sp) * CREC]);

  float total = 0.f, acc = 0.f;
#pragma unroll
  for (int sp = 0; sp < CSPLIT; ++sp) {
    const float* rec = &part[(size_t)(h * CSPLIT + sp) * CREC];
    const float mxi = rec[0];
    const float w = (mxi == -INFINITY) ? 0.f : __expf(mxi - gmax);
    total += w * rec[1];
    acc += w * rec[2 + d];
  }
  joined[(size_t)h * HD + d] = (_Float16)(acc / total);
}

// ---------------------------------------------------------------------------
extern "C" void kernel_launch(void* const* d_in, const int* in_sizes, int n_in,
                              void* d_out, int out_size, void* d_ws,
                              size_t ws_size, hipStream_t stream) {
  const float* emb   = (const float*)d_in[0];
  const int*   mask  = (const int*)d_in[1];
  const float* W_qkv = (const float*)d_in[2];
  const float* b_qkv = (const float*)d_in[3];
  const float* W_o   = (const float*)d_in[4];
  const float* b_o   = (const float*)d_in[5];
  float* out = (float*)d_out;

  _Float16* hp = (_Float16*)d_ws;
  _Float16* A16   = hp;                                      // 2048*768
  _Float16* Wq16T = A16 + (size_t)L_SEQ * D_MODEL;           // 2304*768
  _Float16* Wo16T = Wq16T + (size_t)QKV_N * D_MODEL;         // 768*768
  _Float16* q16   = Wo16T + (size_t)D_MODEL * D_MODEL;       // 12*2048*64
  _Float16* k16   = q16 + (size_t)NHEAD * L_SEQ * HD;
  _Float16* v16   = k16 + (size_t)NHEAD * L_SEQ * HD;
  _Float16* v16T  = v16 + (size_t)NHEAD * L_SEQ * HD;        // [768][2048]
  _Float16* J16   = v16T + (size_t)D_MODEL * L_SEQ;          // 2048*768
  float*    part  = (float*)(J16 + (size_t)L_SEQ * D_MODEL); // 12*32*66

  cvt_fused_kernel<<<CVT_A_BLKS + CVT_B_BLKS + CVT_C_BLKS, 256, 0, stream>>>(
      emb, A16, W_qkv, Wq16T, W_o, Wo16T);

  gemm16_kernel<64, 128, _Float16, true>
      <<<dim3(QKV_N / 128, L_SEQ / 64), 256, 0, stream>>>(
          A16, Wq16T, b_qkv, (_Float16*)nullptr, q16, k16, v16, v16T, L_SEQ,
          QKV_N, D_MODEL);

  attn_mega_kernel<<<dim3(L_SEQ / TL + CSPLIT, NHEAD), 256, 0, stream>>>(
      q16, k16, v16, v16T, mask, J16, part);

  cls_combine_kernel<<<NHEAD, 64, 0, stream>>>(part, J16);

  gemm16_kernel<64, 64, float, false>
      <<<dim3(D_MODEL / 64, L_SEQ / 64), 256, 0, stream>>>(
          J16, Wo16T, b_o, out, (_Float16*)nullptr, (_Float16*)nullptr,
          (_Float16*)nullptr, (_Float16*)nullptr, L_SEQ, D_MODEL, D_MODEL);
}

// Round 13
// 125.044 us; speedup vs baseline: 1.1514x; 1.0032x over previous
//
#include <hip/hip_runtime.h>
#include <hip/hip_bf16.h>
#include <cmath>

#define D_MODEL 768
#define NHEAD 12
#define HD 64
#define L_SEQ 2048
#define WIN 128
#define QKV_N (3 * D_MODEL)

typedef _Float16 half8 __attribute__((ext_vector_type(8)));
typedef _Float16 half4v __attribute__((ext_vector_type(4)));
typedef float floatx4 __attribute__((ext_vector_type(4)));

// async global->LDS, 16 B per lane, LDS dst = wave-uniform base + lane*16
#define ASYNC_COPY16(gptr, lptr)                                      \
  __builtin_amdgcn_global_load_lds(                                   \
      (const __attribute__((address_space(1))) void*)(gptr),          \
      (__attribute__((address_space(3))) void*)(lptr), 16, 0, 0)

// ---------------------------------------------------------------------------
// Fused conversions (R12-identical): emb->fp16, W_qkv^T, W_o^T.
// ---------------------------------------------------------------------------
#define CVT_A_BLKS 1536
#define CVT_B_BLKS (36 * 12)
#define CVT_C_BLKS (12 * 12)

__global__ __launch_bounds__(256) void cvt_fused_kernel(
    const float* __restrict__ emb, _Float16* __restrict__ A16,
    const float* __restrict__ W_qkv, _Float16* __restrict__ Wq16T,
    const float* __restrict__ W_o, _Float16* __restrict__ Wo16T) {
  __shared__ float tile[64][68];
  const int bid = blockIdx.x;
  const int tid = threadIdx.x;

  if (bid < CVT_A_BLKS) {
    const int i = (bid * 256 + tid) * 4;
    const float4 v = *reinterpret_cast<const float4*>(&emb[i]);
    half4v h = {(_Float16)v.x, (_Float16)v.y, (_Float16)v.z, (_Float16)v.w};
    *reinterpret_cast<half4v*>(&A16[i]) = h;
    return;
  }
  const float* In;
  _Float16* Out;
  int R, Cn, bx, by;
  if (bid < CVT_A_BLKS + CVT_B_BLKS) {
    const int b = bid - CVT_A_BLKS;
    In = W_qkv; Out = Wq16T; R = D_MODEL; Cn = QKV_N;
    bx = b % 36; by = b / 36;
  } else {
    const int b = bid - CVT_A_BLKS - CVT_B_BLKS;
    In = W_o; Out = Wo16T; R = D_MODEL; Cn = D_MODEL;
    bx = b % 12; by = b / 12;
  }
  const int r0 = by * 64, c0 = bx * 64;
  const int tr = tid >> 4, tc4 = (tid & 15) * 4;
#pragma unroll
  for (int rr = 0; rr < 4; ++rr) {
    const int r = rr * 16 + tr;
    const float4 v =
        *reinterpret_cast<const float4*>(&In[(size_t)(r0 + r) * Cn + c0 + tc4]);
    tile[r][tc4 + 0] = v.x;
    tile[r][tc4 + 1] = v.y;
    tile[r][tc4 + 2] = v.z;
    tile[r][tc4 + 3] = v.w;
  }
  __syncthreads();
#pragma unroll
  for (int cc = 0; cc < 4; ++cc) {
    const int c = cc * 16 + tr;
    half4v h = {(_Float16)tile[tc4 + 0][c], (_Float16)tile[tc4 + 1][c],
                (_Float16)tile[tc4 + 2][c], (_Float16)tile[tc4 + 3][c]};
    *reinterpret_cast<half4v*>(&Out[(size_t)(c0 + c) * R + r0 + tc4]) = h;
  }
}

// ---------------------------------------------------------------------------
// fp16 MFMA GEMM v4 — ISOLATED change vs R12: staging via global_load_lds
// (16 B, async, no VGPR round-trip). LDS rows linear (32 halfs = 64 B);
// bank-conflict-free frag reads via rule-21 both-sides XOR swizzle:
//   LDS slot (r, s) holds global k-seg s ^ swz(r), swz(r)=(r&3)^((r>>2)&3).
//   source seg for lane l = (l&3)^((l>>2)&3)^(l>>4); read seg = same const.
// BM fixed at 64. C/D layout (m89-verified): col=lane&15, row=(lane>>4)*4+j.
// ---------------------------------------------------------------------------
template <int BM, int BN, typename OutT, bool ROPE>
__global__ __launch_bounds__(256) void gemm16_kernel(
    const _Float16* __restrict__ A, const _Float16* __restrict__ BT,
    const float* __restrict__ bias, OutT* __restrict__ C,
    _Float16* __restrict__ q16, _Float16* __restrict__ k16,
    _Float16* __restrict__ v16, _Float16* __restrict__ v16T, int M, int N,
    int K) {
  static_assert(BM == 64, "staging assignment assumes BM==64");
  constexpr int MF = BM / 32;
  constexpr int NF = BN / 32;
  constexpr int NBPW = BN / 64;  // B chunks per wave (A is 1/wave)

  __shared__ __align__(16) _Float16 At[2 * BM * 32];
  __shared__ __align__(16) _Float16 Bt[2 * BN * 32];

  const int tid = threadIdx.x;
  const int row0 = blockIdx.y * BM;
  const int col0 = blockIdx.x * BN;
  const int wv = tid >> 6;
  const int lane = tid & 63;
  const int wr = wv >> 1;
  const int wc = wv & 1;
  const int lrow = lane & 15;
  const int lk = lane >> 4;

  // swizzled k-segment (in halfs): same constant serves source and read side
  const int segg = (((lane & 3) ^ ((lane >> 2) & 3) ^ (lane >> 4)) << 3);

  // per-lane global source pointers (k advances by 32 halfs per tile)
  const _Float16* gA =
      A + (size_t)(row0 + wv * 16 + (lane >> 2)) * K + segg;
  const _Float16* gB[NBPW];
#pragma unroll
  for (int i = 0; i < NBPW; ++i)
    gB[i] = BT + (size_t)(col0 + (wv + 4 * i) * 16 + (lane >> 2)) * K + segg;

  floatx4 acc[MF][NF];
#pragma unroll
  for (int m = 0; m < MF; ++m)
#pragma unroll
    for (int n = 0; n < NF; ++n) acc[m][n] = (floatx4){0.f, 0.f, 0.f, 0.f};

  const int nt = K / 32;

  // prologue: stage tile 0 into buf 0
  ASYNC_COPY16(gA, &At[wv * 512]);
#pragma unroll
  for (int i = 0; i < NBPW; ++i)
    ASYNC_COPY16(gB[i], &Bt[(wv + 4 * i) * 512]);

  int cur = 0;
  for (int t = 0; t < nt; ++t) {
    __syncthreads();  // drains vmcnt: stage(t) complete; prior reads done
    if (t + 1 < nt) {  // async stage t+1 into the other buffer
      const int ko = (t + 1) * 32;
      ASYNC_COPY16(gA + ko, &At[(cur ^ 1) * (BM * 32) + wv * 512]);
#pragma unroll
      for (int i = 0; i < NBPW; ++i)
        ASYNC_COPY16(gB[i] + ko,
                     &Bt[(cur ^ 1) * (BN * 32) + (wv + 4 * i) * 512]);
    }

    const _Float16* a = &At[cur * (BM * 32)];
    const _Float16* b = &Bt[cur * (BN * 32)];
    half8 af[MF], bf[NF];
#pragma unroll
    for (int m = 0; m < MF; ++m)
      af[m] = *reinterpret_cast<const half8*>(
          &a[(wr * (BM / 2) + m * 16 + lrow) * 32 + segg]);
#pragma unroll
    for (int n = 0; n < NF; ++n)
      bf[n] = *reinterpret_cast<const half8*>(
          &b[(wc * (BN / 2) + n * 16 + lrow) * 32 + segg]);
#pragma unroll
    for (int m = 0; m < MF; ++m)
#pragma unroll
      for (int n = 0; n < NF; ++n)
        acc[m][n] = __builtin_amdgcn_mfma_f32_16x16x32_f16(af[m], bf[n],
                                                           acc[m][n], 0, 0, 0);
    cur ^= 1;
  }

  if constexpr (!ROPE) {
#pragma unroll
    for (int m = 0; m < MF; ++m)
#pragma unroll
      for (int n = 0; n < NF; ++n) {
        const int col = col0 + wc * (BN / 2) + n * 16 + lrow;
        const float bb = bias[col];
#pragma unroll
        for (int j = 0; j < 4; ++j) {
          const int row = row0 + wr * (BM / 2) + m * 16 + lk * 4 + j;
          C[(size_t)row * N + col] = (OutT)(acc[m][n][j] + bb);
        }
      }
  } else {
    const int part = col0 / D_MODEL;             // 0=q 1=k 2=v
    const int h = ((col0 % D_MODEL) >> 6) + wc;  // head
    _Float16* dst = (part == 0) ? q16 : (part == 1) ? k16 : v16;
    float bb[4];
#pragma unroll
    for (int n = 0; n < 4; ++n) bb[n] = bias[col0 + wc * 64 + n * 16 + lrow];
    const float inv0 = exp2f(-0.4152410118609203f * (float)lrow);
    const float inv1 = inv0 * 0.01f;  // *10000^(-32/64)
#pragma unroll
    for (int m = 0; m < MF; ++m) {
#pragma unroll
      for (int j = 0; j < 4; ++j) {
        const int l = row0 + wr * (BM / 2) + m * 16 + lk * 4 + j;
        float val[4];
#pragma unroll
        for (int n = 0; n < 4; ++n) val[n] = acc[m][n][j] + bb[n];
        float o[4];
        if (part < 2) {
          float sn0, cs0, sn1, cs1;
          __sincosf((float)l * inv0, &sn0, &cs0);
          __sincosf((float)l * inv1, &sn1, &cs1);
          o[0] = val[0] * cs0 - val[2] * sn0;
          o[1] = val[1] * cs1 - val[3] * sn1;
          o[2] = val[0] * sn0 + val[2] * cs0;
          o[3] = val[1] * sn1 + val[3] * cs1;
        } else {
          o[0] = val[0]; o[1] = val[1]; o[2] = val[2]; o[3] = val[3];
        }
        const size_t base = ((size_t)h * L_SEQ + l) * HD + lrow;
#pragma unroll
        for (int n = 0; n < 4; ++n) dst[base + n * 16] = (_Float16)o[n];
      }
      if (part == 2) {
        const int lb = row0 + wr * (BM / 2) + m * 16 + lk * 4;
#pragma unroll
        for (int n = 0; n < 4; ++n) {
          const int col = h * HD + n * 16 + lrow;
          half4v hv = {(_Float16)(acc[m][n][0] + bb[n]),
                       (_Float16)(acc[m][n][1] + bb[n]),
                       (_Float16)(acc[m][n][2] + bb[n]),
                       (_Float16)(acc[m][n][3] + bb[n])};
          *reinterpret_cast<half4v*>(&v16T[(size_t)col * L_SEQ + lb]) = hv;
        }
      }
    }
  }
}

// ---------------------------------------------------------------------------
// Attention megakernel (R12-identical, validated).
// ---------------------------------------------------------------------------
#define TL 32
#define SLOTS 160
#define LDH 72
#define LDS_S 168
#define LDVT 168
#define CSPLIT 32
#define CROWS (L_SEQ / CSPLIT)  // 64
#define CREC 66

__global__ __launch_bounds__(256) void attn_mega_kernel(
    const _Float16* __restrict__ q16, const _Float16* __restrict__ k16,
    const _Float16* __restrict__ v16, const _Float16* __restrict__ v16T,
    const int* __restrict__ mask, _Float16* __restrict__ joined,
    float* __restrict__ part) {
  const int h = blockIdx.y;
  const int tid = threadIdx.x;
  const float scale = 0.036084391824351615f;  // 1/sqrt(768)

  __shared__ __align__(16) _Float16 kv16[SLOTS * LDH];
  __shared__ __align__(16) float sS[TL * LDS_S];
  __shared__ __align__(16) _Float16 q16l[TL * LDH];
  __shared__ float vbias[SLOTS];

  if (blockIdx.x < (L_SEQ / TL)) {
    const int l0 = blockIdx.x * TL;
    const _Float16* kh = k16 + (size_t)h * L_SEQ * HD;
    const _Float16* qh = q16 + (size_t)h * L_SEQ * HD;

    {
      const int row = tid >> 3, oct = (tid & 7) * 8;
      *reinterpret_cast<half8*>(&q16l[row * LDH + oct]) =
          *reinterpret_cast<const half8*>(&qh[(size_t)(l0 + row) * HD + oct]);
    }
    const _Float16* kwin = kh + (size_t)(l0 - WIN / 2) * HD;
#pragma unroll
    for (int c = tid; c < SLOTS * 8; c += 256) {
      const int slot = c >> 3, oct = (c & 7) * 8;
      *reinterpret_cast<half8*>(&kv16[slot * LDH + oct]) =
          *reinterpret_cast<const half8*>(&kwin[(size_t)slot * HD + oct]);
    }
    if (tid < SLOTS) {
      const int raw = l0 + tid - WIN / 2;
      const int idx = min(max(raw, 0), L_SEQ - 1);
      vbias[tid] =
          ((raw >= 0) && (raw < L_SEQ) && (mask[idx] != 0)) ? 0.f : -INFINITY;
    }
    __syncthreads();

    const int wv = tid >> 6, lane = tid & 63;
    const int wr = wv >> 1, wc = wv & 1;
    const int lcol = lane & 15, loct = (lane >> 4) * 8;

    floatx4 accS[5];
#pragma unroll
    for (int f = 0; f < 5; ++f) accS[f] = (floatx4){0.f, 0.f, 0.f, 0.f};
#pragma unroll
    for (int ks = 0; ks < 2; ++ks) {
      const half8 af = *reinterpret_cast<const half8*>(
          &q16l[(wr * 16 + lcol) * LDH + ks * 32 + loct]);
#pragma unroll
      for (int f = 0; f < 5; ++f) {
        const half8 bf = *reinterpret_cast<const half8*>(
            &kv16[(wc * 80 + f * 16 + lcol) * LDH + ks * 32 + loct]);
        accS[f] =
            __builtin_amdgcn_mfma_f32_16x16x32_f16(af, bf, accS[f], 0, 0, 0);
      }
    }
#pragma unroll
    for (int f = 0; f < 5; ++f) {
      const int slot = wc * 80 + f * 16 + lcol;
      const float vb = vbias[slot];
#pragma unroll
      for (int j = 0; j < 4; ++j) {
        const int row = wr * 16 + (lane >> 4) * 4 + j;
        const bool inband = (slot >= row) && (slot <= row + WIN - 1);
        sS[row * LDS_S + slot] = inband ? (accS[f][j] * scale + vb) : -INFINITY;
      }
    }
    __syncthreads();

    _Float16* vt = kv16;
    const _Float16* vtg = v16T + (size_t)h * HD * L_SEQ + (l0 - WIN / 2);
#pragma unroll
    for (int c = tid; c < HD * 20; c += 256) {
      const int d = c / 20, seg = c % 20;
      *reinterpret_cast<half8*>(&vt[d * LDVT + seg * 8]) =
          *reinterpret_cast<const half8*>(&vtg[(size_t)d * L_SEQ + seg * 8]);
    }

    const int r = tid >> 3, wg = tid & 7;
    float pv[20];
    float mloc = -INFINITY;
#pragma unroll
    for (int i = 0; i < 20; ++i) {
      pv[i] = sS[r * LDS_S + wg * 20 + i];
      mloc = fmaxf(mloc, pv[i]);
    }
#pragma unroll
    for (int m = 1; m < 8; m <<= 1) mloc = fmaxf(mloc, __shfl_xor(mloc, m));
    float ssum = 0.f;
#pragma unroll
    for (int i = 0; i < 20; ++i) {
      pv[i] = __expf(pv[i] - mloc);
      ssum += pv[i];
    }
#pragma unroll
    for (int m = 1; m < 8; m <<= 1) ssum += __shfl_xor(ssum, m);
    const float rcp = 1.0f / ssum;
    __syncthreads();

    _Float16* pS = reinterpret_cast<_Float16*>(sS);
#pragma unroll
    for (int i = 0; i < 20; ++i)
      pS[r * (2 * LDS_S) + wg * 20 + i] = (_Float16)(pv[i] * rcp);
    __syncthreads();

    floatx4 accO[2];
    accO[0] = (floatx4){0.f, 0.f, 0.f, 0.f};
    accO[1] = (floatx4){0.f, 0.f, 0.f, 0.f};
#pragma unroll
    for (int ks = 0; ks < 5; ++ks) {
      const half8 ap = *reinterpret_cast<const half8*>(
          &pS[(wr * 16 + lcol) * (2 * LDS_S) + ks * 32 + loct]);
#pragma unroll
      for (int cf = 0; cf < 2; ++cf) {
        const half8 bv = *reinterpret_cast<const half8*>(
            &vt[(wc * 32 + cf * 16 + lcol) * LDVT + ks * 32 + loct]);
        accO[cf] =
            __builtin_amdgcn_mfma_f32_16x16x32_f16(ap, bv, accO[cf], 0, 0, 0);
      }
    }
#pragma unroll
    for (int cf = 0; cf < 2; ++cf)
#pragma unroll
      for (int j = 0; j < 4; ++j) {
        const int row = wr * 16 + (lane >> 4) * 4 + j;
        const int d = wc * 32 + cf * 16 + lcol;
        joined[(size_t)(l0 + row) * D_MODEL + h * HD + d] =
            (_Float16)accO[cf][j];
      }
  } else {
    const int sp = blockIdx.x - (L_SEQ / TL);
    const int l0 = sp * CROWS;
    float* scS = sS;
    float* red = sS + CROWS;
    float* pvS = sS + CROWS + 256;

    const _Float16* kh = k16 + (size_t)h * L_SEQ * HD;
    const _Float16* vh = v16 + (size_t)h * L_SEQ * HD;

    const int lq = tid >> 4;
    const int dq = tid & 15;
    const half4v q4 =
        *reinterpret_cast<const half4v*>(&q16[(size_t)h * L_SEQ * HD + dq * 4]);
#pragma unroll
    for (int it = 0; it < CROWS / 16; ++it) {
      const int l = l0 + it * 16 + lq;
      const half4v k4 =
          *reinterpret_cast<const half4v*>(&kh[(size_t)l * HD + dq * 4]);
      float p = (float)q4[0] * (float)k4[0] + (float)q4[1] * (float)k4[1] +
                (float)q4[2] * (float)k4[2] + (float)q4[3] * (float)k4[3];
#pragma unroll
      for (int m = 1; m < 16; m <<= 1) p += __shfl_xor(p, m);
      if (dq == 0) scS[it * 16 + lq] = (mask[l] != 0) ? p * scale : -INFINITY;
    }
    __syncthreads();

    red[tid] = (tid < CROWS) ? scS[tid] : -INFINITY;
    __syncthreads();
    for (int off = 128; off > 0; off >>= 1) {
      if (tid < off) red[tid] = fmaxf(red[tid], red[tid + off]);
      __syncthreads();
    }
    const float mx = red[0];
    __syncthreads();

    float e = 0.f;
    if (tid < CROWS) {
      e = (mx == -INFINITY) ? 0.f : __expf(scS[tid] - mx);
      scS[tid] = e;
    }
    red[tid] = e;
    __syncthreads();
    for (int off = 128; off > 0; off >>= 1) {
      if (tid < off) red[tid] += red[tid + off];
      __syncthreads();
    }
    const float lsum = red[0];
    __syncthreads();

    const int lg = tid >> 6;
    const int d = tid & 63;
    float acc = 0.f;
#pragma unroll 8
    for (int it = 0; it < CROWS / 4; ++it) {
      const int ll = lg + it * 4;
      acc += scS[ll] * (float)vh[(size_t)(l0 + ll) * HD + d];
    }
    pvS[lg * HD + d] = acc;
    __syncthreads();

    float* rec = &part[(size_t)(h * CSPLIT + sp) * CREC];
    if (tid == 0) {
      rec[0] = mx;
      rec[1] = lsum;
    }
    if (tid < HD)
      rec[2 + tid] = pvS[0 * HD + tid] + pvS[1 * HD + tid] +
                     pvS[2 * HD + tid] + pvS[3 * HD + tid];
  }
}

__global__ __launch_bounds__(64) void cls_combine_kernel(
    const float* __restrict__ part, _Float16* __restrict__ joined) {
  const int h = blockIdx.x;
  const int d = threadIdx.x;

  float gmax = -INFINITY;
#pragma unroll
  for (int sp = 0; sp < CSPLIT; ++sp)
    gmax = fmaxf(gmax, part[(size_t)(h * CSPLIT + sp) * CREC]);

  float total = 0.f, acc = 0.f;
#pragma unroll
  for (int sp = 0; sp < CSPLIT; ++sp) {
    const float* rec = &part[(size_t)(h * CSPLIT + sp) * CREC];
    const float mxi = rec[0];
    const float w = (mxi == -INFINITY) ? 0.f : __expf(mxi - gmax);
    total += w * rec[1];
    acc += w * rec[2 + d];
  }
  joined[(size_t)h * HD + d] = (_Float16)(acc / total);
}

// ---------------------------------------------------------------------------
extern "C" void kernel_launch(void* const* d_in, const int* in_sizes, int n_in,
                              void* d_out, int out_size, void* d_ws,
                              size_t ws_size, hipStream_t stream) {
  const float* emb   = (const float*)d_in[0];
  const int*   mask  = (const int*)d_in[1];
  const float* W_qkv = (const float*)d_in[2];
  const float* b_qkv = (const float*)d_in[3];
  const float* W_o   = (const float*)d_in[4];
  const float* b_o   = (const float*)d_in[5];
  float* out = (float*)d_out;

  _Float16* hp = (_Float16*)d_ws;
  _Float16* A16   = hp;                                      // 2048*768
  _Float16* Wq16T = A16 + (size_t)L_SEQ * D_MODEL;           // 2304*768
  _Float16* Wo16T = Wq16T + (size_t)QKV_N * D_MODEL;         // 768*768
  _Float16* q16   = Wo16T + (size_t)D_MODEL * D_MODEL;       // 12*2048*64
  _Float16* k16   = q16 + (size_t)NHEAD * L_SEQ * HD;
  _Float16* v16   = k16 + (size_t)NHEAD * L_SEQ * HD;
  _Float16* v16T  = v16 + (size_t)NHEAD * L_SEQ * HD;        // [768][2048]
  _Float16* J16   = v16T + (size_t)D_MODEL * L_SEQ;          // 2048*768
  float*    part  = (float*)(J16 + (size_t)L_SEQ * D_MODEL); // 12*32*66

  cvt_fused_kernel<<<CVT_A_BLKS + CVT_B_BLKS + CVT_C_BLKS, 256, 0, stream>>>(
      emb, A16, W_qkv, Wq16T, W_o, Wo16T);

  gemm16_kernel<64, 128, _Float16, true>
      <<<dim3(QKV_N / 128, L_SEQ / 64), 256, 0, stream>>>(
          A16, Wq16T, b_qkv, (_Float16*)nullptr, q16, k16, v16, v16T, L_SEQ,
          QKV_N, D_MODEL);

  attn_mega_kernel<<<dim3(L_SEQ / TL + CSPLIT, NHEAD), 256, 0, stream>>>(
      q16, k16, v16, v16T, mask, J16, part);

  cls_combine_kernel<<<NHEAD, 64, 0, stream>>>(part, J16);

  gemm16_kernel<64, 64, float, false>
      <<<dim3(D_MODEL / 64, L_SEQ / 64), 256, 0, stream>>>(
          J16, Wo16T, b_o, out, (_Float16*)nullptr, (_Float16*)nullptr,
          (_Float16*)nullptr, (_Float16*)nullptr, L_SEQ, D_MODEL, D_MODEL);
}